// Round 1
// baseline (310.567 us; speedup 1.0000x reference)
//
#include <hip/hip_runtime.h>

// BackprojectDepth: out[b, 0:3, n] = depth[b, n] * (invK[b,0:3,0:3] @ [x, y, 1]),
//                   out[b, 3, n]   = 1.0
// where x = n % W + dxy[b,0], y = n / W + dxy[b,1].
// B=32, H=512, W=1024. Pure streaming kernel: 64 MB read + 256 MB write.

#define BB 32
#define HH 512
#define WW 1024
#define HWN (HH * WW)   // 524288

__global__ __launch_bounds__(256) void backproject_kernel(
    const float* __restrict__ depth,   // [B, 1, H, W]
    const float* __restrict__ invK,    // [B, 4, 4]
    const int*   __restrict__ dxy,     // [B, 2]
    float*       __restrict__ out)     // [B, 4, H*W]
{
    const int b  = blockIdx.y;                               // wave-uniform
    const int n0 = (blockIdx.x * 256 + threadIdx.x) * 4;     // first pixel of quad

    // Uniform (scalar) loads: 3x3 of invK, dxy
    const float k00 = invK[b * 16 + 0];
    const float k01 = invK[b * 16 + 1];
    const float k02 = invK[b * 16 + 2];
    const float k10 = invK[b * 16 + 4];
    const float k11 = invK[b * 16 + 5];
    const float k12 = invK[b * 16 + 6];
    const float k20 = invK[b * 16 + 8];
    const float k21 = invK[b * 16 + 9];
    const float k22 = invK[b * 16 + 10];
    const float dx  = (float)dxy[b * 2 + 0];
    const float dy  = (float)dxy[b * 2 + 1];

    // depth quad (coalesced 16B load)
    const float4 d = *(const float4*)(depth + (size_t)b * HWN + n0);

    // y constant within the quad (W=1024 multiple of 4, n0 4-aligned)
    const float y  = (float)(n0 >> 10) + dy;        // n0 / W
    const float x0 = (float)(n0 & (WW - 1)) + dx;   // n0 % W

    // Hoist the y/1 part of each row once
    const float c0 = k01 * y + k02;
    const float c1 = k11 * y + k12;
    const float c2 = k21 * y + k22;

    float4 r0, r1, r2;
    r0.x = d.x * (k00 * (x0 + 0.f) + c0);
    r0.y = d.y * (k00 * (x0 + 1.f) + c0);
    r0.z = d.z * (k00 * (x0 + 2.f) + c0);
    r0.w = d.w * (k00 * (x0 + 3.f) + c0);

    r1.x = d.x * (k10 * (x0 + 0.f) + c1);
    r1.y = d.y * (k10 * (x0 + 1.f) + c1);
    r1.z = d.z * (k10 * (x0 + 2.f) + c1);
    r1.w = d.w * (k10 * (x0 + 3.f) + c1);

    r2.x = d.x * (k20 * (x0 + 0.f) + c2);
    r2.y = d.y * (k20 * (x0 + 1.f) + c2);
    r2.z = d.z * (k20 * (x0 + 2.f) + c2);
    r2.w = d.w * (k20 * (x0 + 3.f) + c2);

    float* outb = out + (size_t)b * 4 * HWN;
    *(float4*)(outb + 0 * HWN + n0) = r0;
    *(float4*)(outb + 1 * HWN + n0) = r1;
    *(float4*)(outb + 2 * HWN + n0) = r2;
    *(float4*)(outb + 3 * HWN + n0) = make_float4(1.f, 1.f, 1.f, 1.f);
}

extern "C" void kernel_launch(void* const* d_in, const int* in_sizes, int n_in,
                              void* d_out, int out_size, void* d_ws, size_t ws_size,
                              hipStream_t stream) {
    const float* depth = (const float*)d_in[0];
    const float* invK  = (const float*)d_in[1];
    const int*   dxy   = (const int*)d_in[2];
    float*       out   = (float*)d_out;

    // 512 blocks cover HW/(256*4) pixels per batch; blockIdx.y = batch
    dim3 grid(HWN / (256 * 4), BB);
    backproject_kernel<<<grid, 256, 0, stream>>>(depth, invK, dxy, out);
}